// Round 3
// baseline (543.706 us; speedup 1.0000x reference)
//
#include <hip/hip_runtime.h>
#include <hip/hip_bf16.h>

#define NPTS    524288
#define NG      64
#define GSZ     64
#define VOX     (GSZ*GSZ*GSZ)       // 262144
#define NODES   64
#define TILE    64                  // points per block
#define NBLK    (NPTS / TILE)       // 8192
#define K0      192                 // padded K for layer-0 (164 -> 192)
#define SF      200                 // F row stride (bf16); 400B rows -> only 2-way LDS aliasing
#define WLCAP   2048                // worklist cap; overflow handled inline (p ~ 0)

typedef __attribute__((ext_vector_type(8))) short bf16x8;
typedef __attribute__((ext_vector_type(4))) float f32x4;

__device__ inline unsigned short f2bf(float f) {
    __hip_bfloat16 b = __float2bfloat16(f);
    union { __hip_bfloat16 h; unsigned short u; } cv; cv.h = b;
    return cv.u;
}
__device__ inline unsigned int pk2(float c0, float c1) {
    return (unsigned int)f2bf(c0) | ((unsigned int)f2bf(c1) << 16);
}
__device__ inline float bflo(unsigned int v) { return __uint_as_float(v << 16); }
__device__ inline float bfhi(unsigned int v) { return __uint_as_float(v & 0xffff0000u); }

// ---- prep A: [G,C,64^3] fp32 -> x-duplicated packed pairs:
// dup[g*VOX + (z*64+y)*64 + x] = uint2{ pack(c0,c1)[x], pack(c0,c1)[min(x+1,63)] }
__global__ void dup_prep(const float* __restrict__ fg, uint2* __restrict__ dup) {
    int idx = blockIdx.x * blockDim.x + threadIdx.x;    // NG*VOX/4 threads
    int g = idx >> 16;
    int rem = idx & 65535;
    int row = rem >> 4;            // z*64+y
    int xq = (rem & 15) * 4;       // 0,4,...,60
    const float* c0b = fg + (size_t)g * (2 * VOX) + row * 64 + xq;
    const float* c1b = c0b + VOX;
    float4 a = *(const float4*)c0b;
    float4 b = *(const float4*)c1b;
    int nxt = (xq == 60) ? 3 : 4;  // clamp x+1 at 63
    float an = c0b[nxt], bn = c1b[nxt];
    unsigned int p0 = pk2(a.x, b.x), p1 = pk2(a.y, b.y);
    unsigned int p2 = pk2(a.z, b.z), p3 = pk2(a.w, b.w), p4 = pk2(an, bn);
    uint2* d = dup + ((size_t)g << 18) + row * 64 + xq;
    *(uint4*)(d)     = make_uint4(p0, p1, p1, p2);
    *(uint4*)(d + 2) = make_uint4(p2, p3, p3, p4);
}

// ---- prep B (no-dup fallback): packed bf16x2 voxels ----
__global__ void vox_prep(const float* __restrict__ fg, unsigned int* __restrict__ vox) {
    int i = blockIdx.x * blockDim.x + threadIdx.x;
    int g = i >> 18;
    int v = i & (VOX - 1);
    vox[i] = pk2(fg[(size_t)g * (2 * VOX) + v], fg[(size_t)g * (2 * VOX) + VOX + v]);
}

// ---- weight prep: W0 [164,64] -> bf16 [64][192] (zero-pad); W1 [64,64] -> bf16 [64][64] ----
__global__ void w_prep(const float* __restrict__ W0, const float* __restrict__ W1,
                       unsigned short* __restrict__ w0t, unsigned short* __restrict__ w1t) {
    int t = blockIdx.x * blockDim.x + threadIdx.x;      // 16 blocks x 256
    for (int i = t; i < NODES * K0; i += 4096) {
        int n = i / K0, k = i - n * K0;
        w0t[i] = (k < 164) ? f2bf(W0[k * NODES + n]) : (unsigned short)0;
    }
    for (int i = t; i < NODES * NODES; i += 4096) {
        int n = i >> 6, k = i & 63;
        w1t[i] = f2bf(W1[k * NODES + n]);
    }
}

// ---- gather one (pt, g) pair and write packed feature to Fsh ----
template<int MODE>  // 2 = dup pairs, 1 = packed vox
__device__ inline void gather_pair(int pt, int g,
                                   const uint2* __restrict__ dup,
                                   const unsigned int* __restrict__ vox,
                                   const float* xs, const float* gss, const float* gts,
                                   unsigned short* Fsh) {
    float px = xs[pt * 3 + 0], py = xs[pt * 3 + 1], pz = xs[pt * 3 + 2];
    float ix = (px * gss[g * 3 + 0] + gts[g * 3 + 0] + 1.0f) * 31.5f;
    float iy = (py * gss[g * 3 + 1] + gts[g * 3 + 1] + 1.0f) * 31.5f;
    float iz = (pz * gss[g * 3 + 2] + gts[g * 3 + 2] + 1.0f) * 31.5f;
    float fx = floorf(ix), fy = floorf(iy), fz = floorf(iz);
    int x0 = (int)fx, y0 = (int)fy, z0 = (int)fz;
    float wx = ix - fx, wy = iy - fy, wz = iz - fz;
    float wxa0 = (x0 >= 0) ? (1.0f - wx) : 0.0f;
    float wxa1 = (x0 < 63) ? wx : 0.0f;
    float wya0 = (y0 >= 0) ? (1.0f - wy) : 0.0f;
    float wya1 = (y0 < 63) ? wy : 0.0f;
    float wza0 = (z0 >= 0) ? (1.0f - wz) : 0.0f;
    float wza1 = (z0 < 63) ? wz : 0.0f;
    int yc0 = max(y0, 0), yc1 = min(y0 + 1, 63);
    int zc0 = max(z0, 0), zc1 = min(z0 + 1, 63);
    float f0 = 0.f, f1 = 0.f;
    if (MODE == 2) {
        int xb = min(max(x0, 0), 63);
        const uint2* vg = dup + ((size_t)g << 18);
        #pragma unroll
        for (int dz = 0; dz < 2; ++dz) {
            int zc = dz ? zc1 : zc0; float wzv = dz ? wza1 : wza0;
            #pragma unroll
            for (int dy = 0; dy < 2; ++dy) {
                int yc = dy ? yc1 : yc0; float wyv = dy ? wya1 : wya0;
                uint2 p = vg[(((zc << 6) + yc) << 6) + xb];
                unsigned int pc1 = (x0 >= 0) ? p.y : p.x;   // x0==-1: corner1 is voxel 0 = p.x
                float wzy = wzv * wyv;
                f0 += wzy * (wxa0 * bflo(p.x) + wxa1 * bflo(pc1));
                f1 += wzy * (wxa0 * bfhi(p.x) + wxa1 * bfhi(pc1));
            }
        }
    } else {
        int xc0 = max(x0, 0), xc1 = min(x0 + 1, 63);
        const unsigned int* vg = vox + ((size_t)g << 18);
        #pragma unroll
        for (int dz = 0; dz < 2; ++dz) {
            int zc = dz ? zc1 : zc0; float wzv = dz ? wza1 : wza0;
            #pragma unroll
            for (int dy = 0; dy < 2; ++dy) {
                int yc = dy ? yc1 : yc0; float wyv = dy ? wya1 : wya0;
                int rowb = ((zc << 6) + yc) << 6;
                float wzy = wzv * wyv;
                unsigned int v0 = vg[rowb + xc0], v1 = vg[rowb + xc1];
                f0 += wzy * (wxa0 * bflo(v0) + wxa1 * bflo(v1));
                f1 += wzy * (wxa0 * bfhi(v0) + wxa1 * bfhi(v1));
            }
        }
    }
    *(unsigned int*)&Fsh[pt * SF + 36 + 2 * g] = pk2(f0, f1);
}

// ---- main fused kernel ----
template<int MODE>
__global__ void __launch_bounds__(256, 5)
amrsrn_main(const float* __restrict__ x,
            const float* __restrict__ gscale,
            const float* __restrict__ gtrans,
            const uint2* __restrict__ dup,
            const unsigned int* __restrict__ vox,
            const unsigned short* __restrict__ w0t,
            const unsigned short* __restrict__ w1t,
            const float* __restrict__ b0,
            const float* __restrict__ b1,
            const float* __restrict__ W2,
            const float* __restrict__ b2,
            float* __restrict__ out) {
    __shared__ unsigned short Fsh[TILE * SF];   // 25600 B
    __shared__ unsigned short wl[WLCAP];        // 4096 B
    __shared__ float xs[TILE * 3];
    __shared__ float gss[NG * 3];
    __shared__ float gts[NG * 3];
    __shared__ int wl_cnt;

    const int tid = threadIdx.x;
    const int lane = tid & 63;
    const int gptbase = blockIdx.x * TILE;

    // ---- phase 0: zero F, stage tables ----
    for (int i = tid; i < TILE * SF / 8; i += 256) ((uint4*)Fsh)[i] = make_uint4(0,0,0,0);
    if (tid < TILE * 3) xs[tid] = x[gptbase * 3 + tid];
    if (tid < NG * 3) { gss[tid] = gscale[tid]; gts[tid] = gtrans[tid]; }
    if (tid == 0) wl_cnt = 0;
    __syncthreads();

    // ---- phase 1a: positional encoding (cols 0..35) ----
    {
        int pt = tid & 63;
        int grp = tid >> 6;
        #pragma unroll
        for (int t = 0; t < 9; ++t) {
            int tau = grp * 9 + t;
            int tt = (tau < 18) ? tau : tau - 18;
            int l = tt / 3, d = tt - l * 3;
            float ang = xs[pt * 3 + d] * (3.14159265358979323846f * (float)(1 << l));
            float val = (tau < 18) ? __sinf(ang) : __cosf(ang);
            Fsh[pt * SF + tau] = f2bf(val);
        }
    }

    // ---- phase 1b: scan 64x64 pairs -> worklist (overflow: gather inline) ----
    {
        int pt = tid & 63;
        int gbase = (tid >> 6) * 16;
        float px = xs[pt * 3 + 0], py = xs[pt * 3 + 1], pz = xs[pt * 3 + 2];
        for (int gi = 0; gi < 16; ++gi) {
            int g = gbase + gi;
            float ix = (px * gss[g * 3 + 0] + gts[g * 3 + 0] + 1.0f) * 31.5f;
            float iy = (py * gss[g * 3 + 1] + gts[g * 3 + 1] + 1.0f) * 31.5f;
            float iz = (pz * gss[g * 3 + 2] + gts[g * 3 + 2] + 1.0f) * 31.5f;
            bool valid = (ix >= -1.0f) & (ix < 64.0f)
                       & (iy >= -1.0f) & (iy < 64.0f)
                       & (iz >= -1.0f) & (iz < 64.0f);
            unsigned long long m = __ballot(valid);
            if (m) {
                int base = 0;
                if (lane == 0) base = atomicAdd(&wl_cnt, __popcll(m));
                base = __shfl(base, 0);
                if (valid) {
                    int slot = base + __popcll(m & ((1ull << lane) - 1ull));
                    if (slot < WLCAP) {
                        wl[slot] = (unsigned short)((pt << 6) | g);
                    } else {
                        gather_pair<MODE>(pt, g, dup, vox, xs, gss, gts, Fsh);
                    }
                }
            }
        }
    }
    __syncthreads();

    // ---- phase 2: process worklist ----
    {
        int n = min(wl_cnt, WLCAP);
        for (int i = tid; i < n; i += 256) {
            int e = wl[i];
            gather_pair<MODE>(e >> 6, e & 63, dup, vox, xs, gss, gts, Fsh);
        }
    }
    __syncthreads();

    // ---- phase 3: MFMA MLP. wave w owns pts [16w, 16w+16) ----
    const int wv = tid >> 6;
    const int ptb = wv * 16;
    const int row = lane & 15;
    const int quad = lane >> 4;
    const int koff = quad * 8;

    f32x4 acc0[4] = {{0,0,0,0},{0,0,0,0},{0,0,0,0},{0,0,0,0}};
    #pragma unroll
    for (int ks = 0; ks < 6; ++ks) {
        bf16x8 a = *(const bf16x8*)&Fsh[(ptb + row) * SF + ks * 32 + koff];
        #pragma unroll
        for (int nt = 0; nt < 4; ++nt) {
            bf16x8 b = *(const bf16x8*)&w0t[(nt * 16 + row) * K0 + ks * 32 + koff];
            acc0[nt] = __builtin_amdgcn_mfma_f32_16x16x32_bf16(a, b, acc0[nt], 0, 0, 0);
        }
    }
    #pragma unroll
    for (int nt = 0; nt < 4; ++nt) {
        int node = nt * 16 + row;
        float bb = b0[node];
        #pragma unroll
        for (int r = 0; r < 4; ++r) {
            float h = acc0[nt][r] + bb;
            float s = __sinf(h);
            h = 0.5f * h + s * s;
            Fsh[(ptb + quad * 4 + r) * SF + node] = f2bf(h);
        }
    }

    f32x4 acc1[4] = {{0,0,0,0},{0,0,0,0},{0,0,0,0},{0,0,0,0}};
    #pragma unroll
    for (int ks = 0; ks < 2; ++ks) {
        bf16x8 a = *(const bf16x8*)&Fsh[(ptb + row) * SF + ks * 32 + koff];
        #pragma unroll
        for (int nt = 0; nt < 4; ++nt) {
            bf16x8 b = *(const bf16x8*)&w1t[(nt * 16 + row) * NODES + ks * 32 + koff];
            acc1[nt] = __builtin_amdgcn_mfma_f32_16x16x32_bf16(a, b, acc1[nt], 0, 0, 0);
        }
    }
    float part[4] = {0.f, 0.f, 0.f, 0.f};
    #pragma unroll
    for (int nt = 0; nt < 4; ++nt) {
        int node = nt * 16 + row;
        float b1v = b1[node];
        float w2v = W2[node];
        #pragma unroll
        for (int r = 0; r < 4; ++r) {
            float h = acc1[nt][r] + b1v;
            float s = __sinf(h);
            h = 0.5f * h + s * s;
            part[r] += h * w2v;
        }
    }
    #pragma unroll
    for (int m = 1; m < 16; m <<= 1) {
        #pragma unroll
        for (int r = 0; r < 4; ++r) part[r] += __shfl_xor(part[r], m);
    }
    if (row == 0) {
        float b2v = b2[0];
        int gp = gptbase + ptb + quad * 4;
        #pragma unroll
        for (int r = 0; r < 4; ++r) out[gp + r] = part[r] + b2v;
    }
}

// ---- fallback (no workspace): direct fp32 kernel ----
__global__ void amrsrn_fallback(const float* __restrict__ x,
                                const float* __restrict__ gscale,
                                const float* __restrict__ gtrans,
                                const float* __restrict__ fg,
                                const float* __restrict__ W0,
                                const float* __restrict__ b0,
                                const float* __restrict__ W1,
                                const float* __restrict__ b1,
                                const float* __restrict__ W2,
                                const float* __restrict__ b2,
                                float* __restrict__ out) {
    int p = blockIdx.x * blockDim.x + threadIdx.x;
    float px = x[p*3+0], py = x[p*3+1], pz = x[p*3+2];
    float h0[NODES];
    #pragma unroll
    for (int j = 0; j < NODES; ++j) h0[j] = b0[j];
    #pragma unroll
    for (int l = 0; l < 6; ++l) {
        float freq = 3.14159265358979323846f * (float)(1 << l);
        #pragma unroll
        for (int d = 0; d < 3; ++d) {
            float v = (d == 0 ? px : (d == 1 ? py : pz)) * freq;
            float s = __sinf(v), c = __cosf(v);
            const float* wrs = W0 + (l*3 + d) * NODES;
            const float* wrc = W0 + (18 + l*3 + d) * NODES;
            #pragma unroll
            for (int j = 0; j < NODES; ++j) h0[j] += s * wrs[j] + c * wrc[j];
        }
    }
    for (int g = 0; g < NG; ++g) {
        float ix = (px * gscale[g*3+0] + gtrans[g*3+0] + 1.0f) * 31.5f;
        float iy = (py * gscale[g*3+1] + gtrans[g*3+1] + 1.0f) * 31.5f;
        float iz = (pz * gscale[g*3+2] + gtrans[g*3+2] + 1.0f) * 31.5f;
        float fxf = floorf(ix), fyf = floorf(iy), fzf = floorf(iz);
        int x0 = (int)fxf, y0 = (int)fyf, z0 = (int)fzf;
        float wx = ix - fxf, wy = iy - fyf, wz = iz - fzf;
        bool any = (x0 >= -1 && x0 < GSZ) && (y0 >= -1 && y0 < GSZ) && (z0 >= -1 && z0 < GSZ);
        if (any) {
            float f0 = 0.f, f1 = 0.f;
            #pragma unroll
            for (int dz = 0; dz < 2; ++dz) {
                int zi = z0 + dz; bool vz = ((unsigned)zi < (unsigned)GSZ);
                int zc = min(max(zi, 0), GSZ - 1);
                float wzf = dz ? wz : 1.f - wz;
                #pragma unroll
                for (int dy = 0; dy < 2; ++dy) {
                    int yi = y0 + dy; bool vy = ((unsigned)yi < (unsigned)GSZ);
                    int yc = min(max(yi, 0), GSZ - 1);
                    float wyf = dy ? wy : 1.f - wy;
                    int rowoff = (zc * GSZ + yc) * GSZ;
                    #pragma unroll
                    for (int dx = 0; dx < 2; ++dx) {
                        int xi = x0 + dx; bool vx = ((unsigned)xi < (unsigned)GSZ);
                        int xc = min(max(xi, 0), GSZ - 1);
                        float w = wzf * wyf * (dx ? wx : 1.f - wx);
                        w = (vz && vy && vx) ? w : 0.f;
                        const float* gp = fg + ((size_t)g << 19);
                        f0 += w * gp[rowoff + xc];
                        f1 += w * gp[VOX + rowoff + xc];
                    }
                }
            }
            const float* wr = W0 + (36 + 2*g) * NODES;
            #pragma unroll
            for (int j = 0; j < NODES; ++j) h0[j] += f0 * wr[j] + f1 * wr[NODES + j];
        }
    }
    #pragma unroll
    for (int j = 0; j < NODES; ++j) { float s = __sinf(h0[j]); h0[j] = 0.5f * h0[j] + s * s; }
    float out_acc = b2[0];
    #pragma unroll
    for (int half = 0; half < 2; ++half) {
        float h1[32];
        #pragma unroll
        for (int j = 0; j < 32; ++j) h1[j] = b1[half*32 + j];
        #pragma unroll
        for (int i = 0; i < NODES; ++i) {
            float a = h0[i];
            const float* w1r = W1 + i * NODES + half*32;
            #pragma unroll
            for (int j = 0; j < 32; ++j) h1[j] += a * w1r[j];
        }
        #pragma unroll
        for (int j = 0; j < 32; ++j) { float s = __sinf(h1[j]); out_acc += (0.5f * h1[j] + s * s) * W2[half*32 + j]; }
    }
    out[p] = out_acc;
}

extern "C" void kernel_launch(void* const* d_in, const int* in_sizes, int n_in,
                              void* d_out, int out_size, void* d_ws, size_t ws_size,
                              hipStream_t stream) {
    const float* x      = (const float*)d_in[0];
    const float* gscale = (const float*)d_in[1];
    const float* gtrans = (const float*)d_in[2];
    const float* fg     = (const float*)d_in[3];
    const float* W0     = (const float*)d_in[4];
    const float* b0     = (const float*)d_in[5];
    const float* W1     = (const float*)d_in[6];
    const float* b1     = (const float*)d_in[7];
    const float* W2     = (const float*)d_in[8];
    const float* b2     = (const float*)d_in[9];
    float* out = (float*)d_out;

    const size_t wt_bytes  = 65536;                                   // w0t 24K + w1t 8K, padded
    const size_t dup_bytes = (size_t)NG * VOX * sizeof(uint2);        // 128 MiB
    const size_t vox_bytes = (size_t)NG * VOX * sizeof(unsigned int); // 64 MiB

    if (ws_size >= wt_bytes + dup_bytes) {
        // path A: x-duplicated pairs (4 loads per valid (pt,grid))
        unsigned short* w0t = (unsigned short*)d_ws;
        unsigned short* w1t = w0t + NODES * K0;
        uint2* dup = (uint2*)((char*)d_ws + wt_bytes);
        dup_prep<<<(NG * VOX / 4) / 256, 256, 0, stream>>>(fg, dup);
        w_prep<<<16, 256, 0, stream>>>(W0, W1, w0t, w1t);
        amrsrn_main<2><<<NBLK, 256, 0, stream>>>(x, gscale, gtrans, dup, nullptr,
                                                 w0t, w1t, b0, b1, W2, b2, out);
    } else if (ws_size >= wt_bytes + vox_bytes) {
        // path B: packed voxels (8 loads per valid pair)
        unsigned short* w0t = (unsigned short*)d_ws;
        unsigned short* w1t = w0t + NODES * K0;
        unsigned int* vox = (unsigned int*)((char*)d_ws + wt_bytes);
        vox_prep<<<(NG * VOX) / 256, 256, 0, stream>>>(fg, vox);
        w_prep<<<16, 256, 0, stream>>>(W0, W1, w0t, w1t);
        amrsrn_main<1><<<NBLK, 256, 0, stream>>>(x, gscale, gtrans, nullptr, vox,
                                                 w0t, w1t, b0, b1, W2, b2, out);
    } else {
        amrsrn_fallback<<<NPTS / 256, 256, 0, stream>>>(
            x, gscale, gtrans, fg, W0, b0, W1, b1, W2, b2, out);
    }
}

// Round 4
// 473.482 us; speedup vs baseline: 1.1483x; 1.1483x over previous
//
#include <hip/hip_runtime.h>
#include <hip/hip_bf16.h>

#define NPTS    524288
#define NG      64
#define GSZ     64
#define VOX     (GSZ*GSZ*GSZ)       // 262144
#define NODES   64
#define TILE    64                  // points per block
#define NBLK    (NPTS / TILE)       // 8192
#define K0      192                 // padded K for layer-0 (164 -> 192)
#define SF      200                 // F row stride (bf16)
#define WLCAP   2048                // worklist cap; overflow gathered inline
#define NCELL   4096                // 16^3 Morton cells

typedef __attribute__((ext_vector_type(8))) short bf16x8;
typedef __attribute__((ext_vector_type(4))) float f32x4;

__device__ inline unsigned short f2bf(float f) {
    __hip_bfloat16 b = __float2bfloat16(f);
    union { __hip_bfloat16 h; unsigned short u; } cv; cv.h = b;
    return cv.u;
}
__device__ inline unsigned int pk2(float c0, float c1) {
    return (unsigned int)f2bf(c0) | ((unsigned int)f2bf(c1) << 16);
}
__device__ inline float bflo(unsigned int v) { return __uint_as_float(v << 16); }
__device__ inline float bfhi(unsigned int v) { return __uint_as_float(v & 0xffff0000u); }

__device__ inline int spread4(int v) {   // 4 bits -> bits 0,3,6,9
    return (v & 1) | ((v & 2) << 2) | ((v & 4) << 4) | ((v & 8) << 6);
}
__device__ inline int cell_of(float px, float py, float pz) {
    int cx = min(max((int)((px + 1.0f) * 8.0f), 0), 15);
    int cy = min(max((int)((py + 1.0f) * 8.0f), 0), 15);
    int cz = min(max((int)((pz + 1.0f) * 8.0f), 0), 15);
    return spread4(cx) | (spread4(cy) << 1) | (spread4(cz) << 2);
}

// ---- prep: [G,C,64^3] fp32 -> [G,64^3] packed bf16x2, vectorized ----
__global__ void vox_prep(const float* __restrict__ fg, uint4* __restrict__ vox4) {
    int idx = blockIdx.x * blockDim.x + threadIdx.x;   // NG*VOX/4 threads
    int g = idx >> 16;
    int v = (idx & 65535) * 4;
    const float* base = fg + (size_t)g * (2 * VOX) + v;
    float4 a = *(const float4*)base;
    float4 b = *(const float4*)(base + VOX);
    vox4[idx] = make_uint4(pk2(a.x, b.x), pk2(a.y, b.y), pk2(a.z, b.z), pk2(a.w, b.w));
}

// ---- weight prep + histogram zero (4096 threads total) ----
__global__ void w_prep(const float* __restrict__ W0, const float* __restrict__ W1,
                       unsigned short* __restrict__ w0t, unsigned short* __restrict__ w1t,
                       int* __restrict__ hist) {
    int t = blockIdx.x * blockDim.x + threadIdx.x;     // 16 x 256 = 4096
    hist[t] = 0;
    for (int i = t; i < NODES * K0; i += 4096) {
        int n = i / K0, k = i - n * K0;
        w0t[i] = (k < 164) ? f2bf(W0[k * NODES + n]) : (unsigned short)0;
    }
    for (int i = t; i < NODES * NODES; i += 4096) {
        int n = i >> 6, k = i & 63;
        w1t[i] = f2bf(W1[k * NODES + n]);
    }
}

// ---- sort 1: per-point cell id + global histogram ----
__global__ void sort_count(const float* __restrict__ x, unsigned short* __restrict__ cell_id,
                           int* __restrict__ hist) {
    int p = blockIdx.x * blockDim.x + threadIdx.x;
    int c = cell_of(x[p * 3 + 0], x[p * 3 + 1], x[p * 3 + 2]);
    cell_id[p] = (unsigned short)c;
    atomicAdd(&hist[c], 1);
}

// ---- sort 2: exclusive scan of 4096 bins (1 block, 256 threads x 16 bins) ----
__global__ void sort_scan(const int* __restrict__ hist, int* __restrict__ offs) {
    __shared__ int partial[256];
    int t = threadIdx.x;
    int loc[16];
    int s = 0;
    #pragma unroll
    for (int i = 0; i < 16; ++i) { loc[i] = s; s += hist[t * 16 + i]; }
    partial[t] = s;
    __syncthreads();
    for (int d = 1; d < 256; d <<= 1) {
        int v = (t >= d) ? partial[t - d] : 0;
        __syncthreads();
        partial[t] += v;
        __syncthreads();
    }
    int base = partial[t] - s;      // exclusive
    #pragma unroll
    for (int i = 0; i < 16; ++i) offs[t * 16 + i] = base + loc[i];
}

// ---- sort 3: scatter points to sorted order (destroys offs) ----
__global__ void sort_scatter(const float* __restrict__ x, const unsigned short* __restrict__ cell_id,
                             int* __restrict__ offs, float4* __restrict__ spts) {
    int p = blockIdx.x * blockDim.x + threadIdx.x;
    int c = cell_id[p];
    int pos = atomicAdd(&offs[c], 1);
    spts[pos] = make_float4(x[p * 3 + 0], x[p * 3 + 1], x[p * 3 + 2], __int_as_float(p));
}

// ---- gather one (pt, g) pair -> packed feature in Fsh ----
__device__ inline void gather_pair(int pt, int g,
                                   const unsigned int* __restrict__ vox,
                                   const float* xs, const float* gss, const float* gts,
                                   unsigned short* Fsh) {
    float px = xs[pt * 3 + 0], py = xs[pt * 3 + 1], pz = xs[pt * 3 + 2];
    float ix = (px * gss[g * 3 + 0] + gts[g * 3 + 0] + 1.0f) * 31.5f;
    float iy = (py * gss[g * 3 + 1] + gts[g * 3 + 1] + 1.0f) * 31.5f;
    float iz = (pz * gss[g * 3 + 2] + gts[g * 3 + 2] + 1.0f) * 31.5f;
    float fx = floorf(ix), fy = floorf(iy), fz = floorf(iz);
    int x0 = (int)fx, y0 = (int)fy, z0 = (int)fz;
    float wx = ix - fx, wy = iy - fy, wz = iz - fz;
    float wxa0 = (x0 >= 0) ? (1.0f - wx) : 0.0f;
    float wxa1 = (x0 < 63) ? wx : 0.0f;
    float wya0 = (y0 >= 0) ? (1.0f - wy) : 0.0f;
    float wya1 = (y0 < 63) ? wy : 0.0f;
    float wza0 = (z0 >= 0) ? (1.0f - wz) : 0.0f;
    float wza1 = (z0 < 63) ? wz : 0.0f;
    int xc0 = max(x0, 0), xc1 = min(x0 + 1, 63);
    int yc0 = max(y0, 0), yc1 = min(y0 + 1, 63);
    int zc0 = max(z0, 0), zc1 = min(z0 + 1, 63);
    const unsigned int* vg = vox + ((size_t)g << 18);
    float f0 = 0.f, f1 = 0.f;
    #pragma unroll
    for (int dz = 0; dz < 2; ++dz) {
        int zc = dz ? zc1 : zc0; float wzv = dz ? wza1 : wza0;
        #pragma unroll
        for (int dy = 0; dy < 2; ++dy) {
            int yc = dy ? yc1 : yc0; float wyv = dy ? wya1 : wya0;
            int rowb = ((zc << 6) + yc) << 6;
            float wzy = wzv * wyv;
            unsigned int v0 = vg[rowb + xc0], v1 = vg[rowb + xc1];
            f0 += wzy * (wxa0 * bflo(v0) + wxa1 * bflo(v1));
            f1 += wzy * (wxa0 * bfhi(v0) + wxa1 * bfhi(v1));
        }
    }
    *(unsigned int*)&Fsh[pt * SF + 36 + 2 * g] = pk2(f0, f1);
}

// ---- main fused kernel (sorted points, indirect output) ----
__global__ void __launch_bounds__(256, 5)
amrsrn_main(const float4* __restrict__ spts,
            const float* __restrict__ gscale,
            const float* __restrict__ gtrans,
            const unsigned int* __restrict__ vox,
            const unsigned short* __restrict__ w0t,
            const unsigned short* __restrict__ w1t,
            const float* __restrict__ b0,
            const float* __restrict__ b1,
            const float* __restrict__ W2,
            const float* __restrict__ b2,
            float* __restrict__ out) {
    __shared__ unsigned short Fsh[TILE * SF];   // 25600 B
    __shared__ unsigned short wl[WLCAP];        // 4096 B
    __shared__ float xs[TILE * 3];
    __shared__ int   sidx[TILE];
    __shared__ float gss[NG * 3];
    __shared__ float gts[NG * 3];
    __shared__ int wl_cnt;

    const int tid = threadIdx.x;
    const int lane = tid & 63;
    // XCD swizzle: round-robin dispatch -> each XCD gets a contiguous Morton range
    const int cb = ((blockIdx.x & 7) << 10) | (blockIdx.x >> 3);
    const int base = cb * TILE;

    // ---- phase 0: zero F, stage points + tables ----
    for (int i = tid; i < TILE * SF / 8; i += 256) ((uint4*)Fsh)[i] = make_uint4(0,0,0,0);
    if (tid < TILE) {
        float4 sp = spts[base + tid];
        xs[tid * 3 + 0] = sp.x; xs[tid * 3 + 1] = sp.y; xs[tid * 3 + 2] = sp.z;
        sidx[tid] = __float_as_int(sp.w);
    }
    if (tid < NG * 3) { gss[tid] = gscale[tid]; gts[tid] = gtrans[tid]; }
    if (tid == 0) wl_cnt = 0;
    __syncthreads();

    // ---- phase 1a: positional encoding (cols 0..35) ----
    {
        int pt = tid & 63;
        int grp = tid >> 6;
        #pragma unroll
        for (int t = 0; t < 9; ++t) {
            int tau = grp * 9 + t;
            int tt = (tau < 18) ? tau : tau - 18;
            int l = tt / 3, d = tt - l * 3;
            float ang = xs[pt * 3 + d] * (3.14159265358979323846f * (float)(1 << l));
            float val = (tau < 18) ? __sinf(ang) : __cosf(ang);
            Fsh[pt * SF + tau] = f2bf(val);
        }
    }

    // ---- phase 1b: scan 64x64 pairs -> worklist ----
    {
        int pt = tid & 63;
        int gbase = (tid >> 6) * 16;
        float px = xs[pt * 3 + 0], py = xs[pt * 3 + 1], pz = xs[pt * 3 + 2];
        for (int gi = 0; gi < 16; ++gi) {
            int g = gbase + gi;
            float ix = (px * gss[g * 3 + 0] + gts[g * 3 + 0] + 1.0f) * 31.5f;
            float iy = (py * gss[g * 3 + 1] + gts[g * 3 + 1] + 1.0f) * 31.5f;
            float iz = (pz * gss[g * 3 + 2] + gts[g * 3 + 2] + 1.0f) * 31.5f;
            bool valid = (ix >= -1.0f) & (ix < 64.0f)
                       & (iy >= -1.0f) & (iy < 64.0f)
                       & (iz >= -1.0f) & (iz < 64.0f);
            unsigned long long m = __ballot(valid);
            if (m) {
                int b = 0;
                if (lane == 0) b = atomicAdd(&wl_cnt, __popcll(m));
                b = __shfl(b, 0);
                if (valid) {
                    int slot = b + __popcll(m & ((1ull << lane) - 1ull));
                    if (slot < WLCAP) wl[slot] = (unsigned short)((pt << 6) | g);
                    else gather_pair(pt, g, vox, xs, gss, gts, Fsh);
                }
            }
        }
    }
    __syncthreads();

    // ---- phase 2: process worklist ----
    {
        int n = min(wl_cnt, WLCAP);
        for (int i = tid; i < n; i += 256) {
            int e = wl[i];
            gather_pair(e >> 6, e & 63, vox, xs, gss, gts, Fsh);
        }
    }
    __syncthreads();

    // ---- phase 3: MFMA MLP. wave w owns pts [16w, 16w+16) ----
    const int wv = tid >> 6;
    const int ptb = wv * 16;
    const int row = lane & 15;
    const int quad = lane >> 4;
    const int koff = quad * 8;

    f32x4 acc0[4] = {{0,0,0,0},{0,0,0,0},{0,0,0,0},{0,0,0,0}};
    #pragma unroll
    for (int ks = 0; ks < 6; ++ks) {
        bf16x8 a = *(const bf16x8*)&Fsh[(ptb + row) * SF + ks * 32 + koff];
        #pragma unroll
        for (int nt = 0; nt < 4; ++nt) {
            bf16x8 b = *(const bf16x8*)&w0t[(nt * 16 + row) * K0 + ks * 32 + koff];
            acc0[nt] = __builtin_amdgcn_mfma_f32_16x16x32_bf16(a, b, acc0[nt], 0, 0, 0);
        }
    }
    #pragma unroll
    for (int nt = 0; nt < 4; ++nt) {
        int node = nt * 16 + row;
        float bb = b0[node];
        #pragma unroll
        for (int r = 0; r < 4; ++r) {
            float h = acc0[nt][r] + bb;
            float s = __sinf(h);
            h = 0.5f * h + s * s;
            Fsh[(ptb + quad * 4 + r) * SF + node] = f2bf(h);
        }
    }

    f32x4 acc1[4] = {{0,0,0,0},{0,0,0,0},{0,0,0,0},{0,0,0,0}};
    #pragma unroll
    for (int ks = 0; ks < 2; ++ks) {
        bf16x8 a = *(const bf16x8*)&Fsh[(ptb + row) * SF + ks * 32 + koff];
        #pragma unroll
        for (int nt = 0; nt < 4; ++nt) {
            bf16x8 b = *(const bf16x8*)&w1t[(nt * 16 + row) * NODES + ks * 32 + koff];
            acc1[nt] = __builtin_amdgcn_mfma_f32_16x16x32_bf16(a, b, acc1[nt], 0, 0, 0);
        }
    }
    float part[4] = {0.f, 0.f, 0.f, 0.f};
    #pragma unroll
    for (int nt = 0; nt < 4; ++nt) {
        int node = nt * 16 + row;
        float b1v = b1[node];
        float w2v = W2[node];
        #pragma unroll
        for (int r = 0; r < 4; ++r) {
            float h = acc1[nt][r] + b1v;
            float s = __sinf(h);
            h = 0.5f * h + s * s;
            part[r] += h * w2v;
        }
    }
    #pragma unroll
    for (int m = 1; m < 16; m <<= 1) {
        #pragma unroll
        for (int r = 0; r < 4; ++r) part[r] += __shfl_xor(part[r], m);
    }
    if (row == 0) {
        float b2v = b2[0];
        #pragma unroll
        for (int r = 0; r < 4; ++r) {
            int pt = ptb + quad * 4 + r;
            out[sidx[pt]] = part[r] + b2v;
        }
    }
}

// ---- fallback (no workspace): direct fp32 kernel ----
__global__ void amrsrn_fallback(const float* __restrict__ x,
                                const float* __restrict__ gscale,
                                const float* __restrict__ gtrans,
                                const float* __restrict__ fg,
                                const float* __restrict__ W0,
                                const float* __restrict__ b0,
                                const float* __restrict__ W1,
                                const float* __restrict__ b1,
                                const float* __restrict__ W2,
                                const float* __restrict__ b2,
                                float* __restrict__ out) {
    int p = blockIdx.x * blockDim.x + threadIdx.x;
    float px = x[p*3+0], py = x[p*3+1], pz = x[p*3+2];
    float h0[NODES];
    #pragma unroll
    for (int j = 0; j < NODES; ++j) h0[j] = b0[j];
    #pragma unroll
    for (int l = 0; l < 6; ++l) {
        float freq = 3.14159265358979323846f * (float)(1 << l);
        #pragma unroll
        for (int d = 0; d < 3; ++d) {
            float v = (d == 0 ? px : (d == 1 ? py : pz)) * freq;
            float s = __sinf(v), c = __cosf(v);
            const float* wrs = W0 + (l*3 + d) * NODES;
            const float* wrc = W0 + (18 + l*3 + d) * NODES;
            #pragma unroll
            for (int j = 0; j < NODES; ++j) h0[j] += s * wrs[j] + c * wrc[j];
        }
    }
    for (int g = 0; g < NG; ++g) {
        float ix = (px * gscale[g*3+0] + gtrans[g*3+0] + 1.0f) * 31.5f;
        float iy = (py * gscale[g*3+1] + gtrans[g*3+1] + 1.0f) * 31.5f;
        float iz = (pz * gscale[g*3+2] + gtrans[g*3+2] + 1.0f) * 31.5f;
        float fxf = floorf(ix), fyf = floorf(iy), fzf = floorf(iz);
        int x0 = (int)fxf, y0 = (int)fyf, z0 = (int)fzf;
        float wx = ix - fxf, wy = iy - fyf, wz = iz - fzf;
        bool any = (x0 >= -1 && x0 < GSZ) && (y0 >= -1 && y0 < GSZ) && (z0 >= -1 && z0 < GSZ);
        if (any) {
            float f0 = 0.f, f1 = 0.f;
            #pragma unroll
            for (int dz = 0; dz < 2; ++dz) {
                int zi = z0 + dz; bool vz = ((unsigned)zi < (unsigned)GSZ);
                int zc = min(max(zi, 0), GSZ - 1);
                float wzf = dz ? wz : 1.f - wz;
                #pragma unroll
                for (int dy = 0; dy < 2; ++dy) {
                    int yi = y0 + dy; bool vy = ((unsigned)yi < (unsigned)GSZ);
                    int yc = min(max(yi, 0), GSZ - 1);
                    float wyf = dy ? wy : 1.f - wy;
                    int rowoff = (zc * GSZ + yc) * GSZ;
                    #pragma unroll
                    for (int dx = 0; dx < 2; ++dx) {
                        int xi = x0 + dx; bool vx = ((unsigned)xi < (unsigned)GSZ);
                        int xc = min(max(xi, 0), GSZ - 1);
                        float w = wzf * wyf * (dx ? wx : 1.f - wx);
                        w = (vz && vy && vx) ? w : 0.f;
                        const float* gp = fg + ((size_t)g << 19);
                        f0 += w * gp[rowoff + xc];
                        f1 += w * gp[VOX + rowoff + xc];
                    }
                }
            }
            const float* wr = W0 + (36 + 2*g) * NODES;
            #pragma unroll
            for (int j = 0; j < NODES; ++j) h0[j] += f0 * wr[j] + f1 * wr[NODES + j];
        }
    }
    #pragma unroll
    for (int j = 0; j < NODES; ++j) { float s = __sinf(h0[j]); h0[j] = 0.5f * h0[j] + s * s; }
    float out_acc = b2[0];
    #pragma unroll
    for (int half = 0; half < 2; ++half) {
        float h1[32];
        #pragma unroll
        for (int j = 0; j < 32; ++j) h1[j] = b1[half*32 + j];
        #pragma unroll
        for (int i = 0; i < NODES; ++i) {
            float a = h0[i];
            const float* w1r = W1 + i * NODES + half*32;
            #pragma unroll
            for (int j = 0; j < 32; ++j) h1[j] += a * w1r[j];
        }
        #pragma unroll
        for (int j = 0; j < 32; ++j) { float s = __sinf(h1[j]); out_acc += (0.5f * h1[j] + s * s) * W2[half*32 + j]; }
    }
    out[p] = out_acc;
}

extern "C" void kernel_launch(void* const* d_in, const int* in_sizes, int n_in,
                              void* d_out, int out_size, void* d_ws, size_t ws_size,
                              hipStream_t stream) {
    const float* x      = (const float*)d_in[0];
    const float* gscale = (const float*)d_in[1];
    const float* gtrans = (const float*)d_in[2];
    const float* fg     = (const float*)d_in[3];
    const float* W0     = (const float*)d_in[4];
    const float* b0     = (const float*)d_in[5];
    const float* W1     = (const float*)d_in[6];
    const float* b1     = (const float*)d_in[7];
    const float* W2     = (const float*)d_in[8];
    const float* b2     = (const float*)d_in[9];
    float* out = (float*)d_out;

    // workspace layout (all within 128 MiB):
    //   [0,        64K)   w0t (24K) + w1t (8K)
    //   [64K,      80K)   hist (4096 int)
    //   [80K,      96K)   offs (4096 int)
    //   [96K,      96K+1M) cell_id (524288 u16)
    //   [+,        +8M)   sorted pts (524288 float4)
    //   [+,        +64M)  vox
    char* wsp = (char*)d_ws;
    unsigned short* w0t = (unsigned short*)wsp;
    unsigned short* w1t = w0t + NODES * K0;
    int* hist           = (int*)(wsp + (64 << 10));
    int* offs           = (int*)(wsp + (80 << 10));
    unsigned short* cid = (unsigned short*)(wsp + (96 << 10));
    float4* spts        = (float4*)(wsp + (96 << 10) + (1 << 20));
    unsigned int* vox   = (unsigned int*)(wsp + (96 << 10) + (1 << 20) + (8 << 20));
    const size_t ws_needed = (96 << 10) + (1 << 20) + (8 << 20) + (size_t)NG * VOX * 4;

    if (ws_size >= ws_needed) {
        vox_prep<<<(NG * VOX / 4) / 256, 256, 0, stream>>>(fg, (uint4*)vox);
        w_prep<<<16, 256, 0, stream>>>(W0, W1, w0t, w1t, hist);
        sort_count<<<NPTS / 256, 256, 0, stream>>>(x, cid, hist);
        sort_scan<<<1, 256, 0, stream>>>(hist, offs);
        sort_scatter<<<NPTS / 256, 256, 0, stream>>>(x, cid, offs, spts);
        amrsrn_main<<<NBLK, 256, 0, stream>>>(spts, gscale, gtrans, vox,
                                              w0t, w1t, b0, b1, W2, b2, out);
    } else {
        amrsrn_fallback<<<NPTS / 256, 256, 0, stream>>>(
            x, gscale, gtrans, fg, W0, b0, W1, b1, W2, b2, out);
    }
}